// Round 2
// baseline (87.973 us; speedup 1.0000x reference)
//
#include <hip/hip_runtime.h>
#include <math.h>

#define NN 28     // nodes
#define NH 64     // hidden dim

// ---------------------------------------------------------------------------
// Kernel 1: build dense normalized adjacency A_hat (28x28) + activation
// constants into d_ws. Single block; trivial cost.
// ws layout (floats): [0..783] A_hat row-major (A[dst*28+src]),
//                     [784]=cpos, [785]=cneg, [786]=flag (0 => b1 all zero)
// NOTE: harness delivers integer inputs as int32 (int64 in reference is
// narrowed) -> edge_index is const int*, src=[0,E), dst=[E,2E).
// ---------------------------------------------------------------------------
__global__ __launch_bounds__(256) void build_graph_kernel(
    const int* __restrict__ ei, int E,
    const float* __restrict__ W1, const float* __restrict__ b1,
    const float* __restrict__ W2, float* __restrict__ ws) {
  __shared__ float dinv[NN];
  __shared__ float A[NN * NN];
  __shared__ float cpos, cneg;
  __shared__ int flag;
  const int t = threadIdx.x;

  if (t < NN) dinv[t] = 1.0f;  // self-loop contributes 1 to every degree
  for (int i = t; i < NN * NN; i += blockDim.x) A[i] = 0.0f;
  if (t == 0) { cpos = 0.0f; cneg = 0.0f; flag = 0; }
  __syncthreads();

  // degree over dst (edges + self loops)
  for (int e = t; e < E; e += blockDim.x) {
    int d = ei[E + e];
    atomicAdd(&dinv[d], 1.0f);
  }
  __syncthreads();
  if (t < NN) dinv[t] = 1.0f / sqrtf(dinv[t]);  // deg >= 1 always
  __syncthreads();

  // scatter normalized edge weights
  for (int e = t; e < E; e += blockDim.x) {
    int s = ei[e];
    int d = ei[E + e];
    atomicAdd(&A[d * NN + s], dinv[s] * dinv[d]);
  }
  if (t < NN) atomicAdd(&A[t * NN + t], dinv[t] * dinv[t]);  // self loops

  // activation constants: f(t) = sum_o relu(W1[o]*t + b1[o]) * W2[o]
  // if b1 == 0: f(t) = t * (t>0 ? cpos : cneg)
  if (t < NH) {
    float w1 = W1[t], w2 = W2[t];
    if (w1 > 0.0f)      atomicAdd(&cpos, w1 * w2);
    else if (w1 < 0.0f) atomicAdd(&cneg, w1 * w2);
    if (b1[t] != 0.0f) atomicOr(&flag, 1);
  }
  __syncthreads();

  for (int i = t; i < NN * NN; i += blockDim.x) ws[i] = A[i];
  if (t == 0) {
    ws[NN * NN]     = cpos;
    ws[NN * NN + 1] = cneg;
    ws[NN * NN + 2] = (float)flag;
  }
}

// ---------------------------------------------------------------------------
// Kernel 2: one thread per batch element.
//   s = A_hat @ x_b          (28x28 matvec, A via uniform loads -> SGPRs)
//   z = f(s)                 (2-slope fast path; exact 64-term fallback)
//   out_b = A_hat @ z + b2
// x rows are 112 B = 7 float4, 16B-aligned -> fully vectorized load/store.
// ---------------------------------------------------------------------------
__global__ __launch_bounds__(256) void gcn_fwd_kernel(
    const float* __restrict__ x, const float* __restrict__ ws,
    const float* __restrict__ W1, const float* __restrict__ b1,
    const float* __restrict__ W2, const float* __restrict__ b2,
    float* __restrict__ out, int B) {
  const int b = blockIdx.x * blockDim.x + threadIdx.x;
  if (b >= B) return;

  // load this batch's 28 inputs (7 x float4, aligned: 28*4 = 112 = 7*16)
  const float4* xp = (const float4*)(x + (size_t)b * NN);
  float xv[NN];
#pragma unroll
  for (int k = 0; k < 7; ++k) {
    float4 v = xp[k];
    xv[4 * k + 0] = v.x; xv[4 * k + 1] = v.y;
    xv[4 * k + 2] = v.z; xv[4 * k + 3] = v.w;
  }

  // s = A @ xv  (A indices are compile-time-uniform -> scalar loads)
  float s[NN];
#pragma unroll
  for (int n = 0; n < NN; ++n) {
    float acc = 0.0f;
#pragma unroll
    for (int m = 0; m < NN; ++m) acc = fmaf(ws[n * NN + m], xv[m], acc);
    s[n] = acc;
  }

  // elementwise activation-contraction
  const float cpos = ws[NN * NN];
  const float cneg = ws[NN * NN + 1];
  const bool  fast = (ws[NN * NN + 2] == 0.0f);

  float z[NN];
  if (fast) {
#pragma unroll
    for (int n = 0; n < NN; ++n)
      z[n] = s[n] * (s[n] > 0.0f ? cpos : cneg);
  } else {
    // general (b1 != 0) path: exact 64-term sum
#pragma unroll
    for (int n = 0; n < NN; ++n) z[n] = 0.0f;
    for (int o = 0; o < NH; ++o) {
      float w1 = W1[o], bb = b1[o], w2 = W2[o];
#pragma unroll
      for (int n = 0; n < NN; ++n)
        z[n] = fmaf(fmaxf(fmaf(s[n], w1, bb), 0.0f), w2, z[n]);
    }
  }

  // out = A @ z + b2
  const float bias2 = b2[0];
  float ov[NN];
#pragma unroll
  for (int n = 0; n < NN; ++n) {
    float acc = bias2;
#pragma unroll
    for (int m = 0; m < NN; ++m) acc = fmaf(ws[n * NN + m], z[m], acc);
    ov[n] = acc;
  }

  float4* op = (float4*)(out + (size_t)b * NN);
#pragma unroll
  for (int k = 0; k < 7; ++k) {
    float4 v;
    v.x = ov[4 * k + 0]; v.y = ov[4 * k + 1];
    v.z = ov[4 * k + 2]; v.w = ov[4 * k + 3];
    op[k] = v;
  }
}

extern "C" void kernel_launch(void* const* d_in, const int* in_sizes, int n_in,
                              void* d_out, int out_size, void* d_ws, size_t ws_size,
                              hipStream_t stream) {
  const float* x  = (const float*)d_in[0];
  const int*   ei = (const int*)d_in[1];
  const float* W1 = (const float*)d_in[2];
  const float* b1 = (const float*)d_in[3];
  const float* W2 = (const float*)d_in[4];
  const float* b2 = (const float*)d_in[5];
  float* out = (float*)d_out;
  float* ws  = (float*)d_ws;

  const int E = in_sizes[1] / 2;       // edge_index is (2, E)
  const int B = in_sizes[0] / NN;      // x is (B, 28)

  build_graph_kernel<<<1, 256, 0, stream>>>(ei, E, W1, b1, W2, ws);

  const int threads = 256;
  const int blocks = (B + threads - 1) / threads;
  gcn_fwd_kernel<<<blocks, threads, 0, stream>>>(x, ws, W1, b1, W2, b2, out, B);
}

// Round 3
// 83.140 us; speedup vs baseline: 1.0581x; 1.0581x over previous
//
#include <hip/hip_runtime.h>
#include <math.h>

#define NN 28     // nodes
#define NH 64     // hidden dim

// ---------------------------------------------------------------------------
// Single fused kernel.
// Phase 1 (per block, redundant): build dense normalized adjacency A_hat
//   (28x28) in LDS from edge_index, plus activation constants
//   cpos/cneg (b1==0 fast path) and a flag for the exact fallback.
//   Cost ~0.5 us/block, runs concurrently across all blocks.
// Phase 2: one thread per batch element:
//   s = A_hat @ x_b      (A via LDS float4 broadcast reads -> no conflicts)
//   z = f(s)             (2-slope fast path; exact 64-term fallback)
//   out_b = A_hat @ z + b2
// x rows are 112 B = 7 float4, 16B-aligned -> fully vectorized global I/O.
// NOTE: harness delivers int64 inputs narrowed to int32 -> ei is const int*,
// src=[0,E), dst=[E,2E).
// ---------------------------------------------------------------------------
__global__ __launch_bounds__(256) void gcn_fused_kernel(
    const float* __restrict__ x, const int* __restrict__ ei, int E,
    const float* __restrict__ W1, const float* __restrict__ b1,
    const float* __restrict__ W2, const float* __restrict__ b2,
    float* __restrict__ out, int B) {
  __shared__ __align__(16) float A[NN * NN];
  __shared__ float dinv[NN];
  __shared__ float cpos_s, cneg_s;
  __shared__ int flag_s;
  const int t = threadIdx.x;

  // ---- Phase 1: build A_hat in LDS ----
  if (t < NN) dinv[t] = 1.0f;  // self-loop contributes 1 to every degree
  for (int i = t; i < NN * NN; i += 256) A[i] = 0.0f;
  if (t == 0) { cpos_s = 0.0f; cneg_s = 0.0f; flag_s = 0; }
  __syncthreads();

  for (int e = t; e < E; e += 256) atomicAdd(&dinv[ei[E + e]], 1.0f);
  __syncthreads();
  if (t < NN) dinv[t] = 1.0f / sqrtf(dinv[t]);  // deg >= 1 always
  __syncthreads();

  for (int e = t; e < E; e += 256) {
    int s = ei[e];
    int d = ei[E + e];
    atomicAdd(&A[d * NN + s], dinv[s] * dinv[d]);
  }
  if (t < NN) atomicAdd(&A[t * NN + t], dinv[t] * dinv[t]);  // self loops

  // activation constants: f(t) = sum_o relu(W1[o]*t + b1[o]) * W2[o]
  // if b1 == 0: f(t) = t * (t>0 ? cpos : cneg)
  if (t < NH) {
    float w1 = W1[t], w2 = W2[t];
    if (w1 > 0.0f)      atomicAdd(&cpos_s, w1 * w2);
    else if (w1 < 0.0f) atomicAdd(&cneg_s, w1 * w2);
    if (b1[t] != 0.0f) atomicOr(&flag_s, 1);
  }
  __syncthreads();

  // ---- Phase 2: per-batch-element compute ----
  const int b = blockIdx.x * 256 + t;
  if (b >= B) return;

  const float4* xp = (const float4*)(x + (size_t)b * NN);
  float xv[NN];
#pragma unroll
  for (int k = 0; k < 7; ++k) {
    float4 v = xp[k];
    xv[4 * k + 0] = v.x; xv[4 * k + 1] = v.y;
    xv[4 * k + 2] = v.z; xv[4 * k + 3] = v.w;
  }

  const float4* A4 = (const float4*)A;  // rows are 7 float4, 112 B aligned

  // s = A @ xv   (LDS broadcast reads, 4 values per ds_read_b128)
  float s[NN];
#pragma unroll
  for (int n = 0; n < NN; ++n) {
    float acc = 0.0f;
#pragma unroll
    for (int k = 0; k < 7; ++k) {
      float4 a = A4[n * 7 + k];
      acc = fmaf(a.x, xv[4 * k + 0], acc);
      acc = fmaf(a.y, xv[4 * k + 1], acc);
      acc = fmaf(a.z, xv[4 * k + 2], acc);
      acc = fmaf(a.w, xv[4 * k + 3], acc);
    }
    s[n] = acc;
  }

  // elementwise activation-contraction
  const float cpos = cpos_s;
  const float cneg = cneg_s;
  const bool  fast = (flag_s == 0);

  float z[NN];
  if (fast) {
#pragma unroll
    for (int n = 0; n < NN; ++n)
      z[n] = s[n] * (s[n] > 0.0f ? cpos : cneg);
  } else {
    // general (b1 != 0) path: exact 64-term sum
#pragma unroll
    for (int n = 0; n < NN; ++n) z[n] = 0.0f;
    for (int o = 0; o < NH; ++o) {
      float w1 = W1[o], bb = b1[o], w2 = W2[o];
#pragma unroll
      for (int n = 0; n < NN; ++n)
        z[n] = fmaf(fmaxf(fmaf(s[n], w1, bb), 0.0f), w2, z[n]);
    }
  }

  // out = A @ z + b2
  const float bias2 = b2[0];
  float ov[NN];
#pragma unroll
  for (int n = 0; n < NN; ++n) {
    float acc = bias2;
#pragma unroll
    for (int k = 0; k < 7; ++k) {
      float4 a = A4[n * 7 + k];
      acc = fmaf(a.x, z[4 * k + 0], acc);
      acc = fmaf(a.y, z[4 * k + 1], acc);
      acc = fmaf(a.z, z[4 * k + 2], acc);
      acc = fmaf(a.w, z[4 * k + 3], acc);
    }
    ov[n] = acc;
  }

  float4* op = (float4*)(out + (size_t)b * NN);
#pragma unroll
  for (int k = 0; k < 7; ++k) {
    float4 v;
    v.x = ov[4 * k + 0]; v.y = ov[4 * k + 1];
    v.z = ov[4 * k + 2]; v.w = ov[4 * k + 3];
    op[k] = v;
  }
}

extern "C" void kernel_launch(void* const* d_in, const int* in_sizes, int n_in,
                              void* d_out, int out_size, void* d_ws, size_t ws_size,
                              hipStream_t stream) {
  const float* x  = (const float*)d_in[0];
  const int*   ei = (const int*)d_in[1];
  const float* W1 = (const float*)d_in[2];
  const float* b1 = (const float*)d_in[3];
  const float* W2 = (const float*)d_in[4];
  const float* b2 = (const float*)d_in[5];
  float* out = (float*)d_out;

  const int E = in_sizes[1] / 2;       // edge_index is (2, E)
  const int B = in_sizes[0] / NN;      // x is (B, 28)

  const int threads = 256;
  const int blocks = (B + threads - 1) / threads;
  gcn_fused_kernel<<<blocks, threads, 0, stream>>>(x, ei, E, W1, b1, W2, b2,
                                                   out, B);
}

// Round 4
// 77.266 us; speedup vs baseline: 1.1386x; 1.0760x over previous
//
#include <hip/hip_runtime.h>
#include <math.h>

#define NN  28    // nodes
#define NH  64    // hidden dim
#define EPB 256   // batch elements per block
#define TPB 512   // threads per block: 2 threads (roles) per element
#define LSTR 29   // padded LDS stride (29 odd -> 2 lanes/bank = conflict-free)

// ---------------------------------------------------------------------------
// Fused kernel, 2 threads per batch element (rows 0-13 / 14-27) for 8 waves/CU
// of latency hiding (was 4 waves/CU = 1/SIMD with 1 thread/element).
// Phase 1 (per block, redundant): dense normalized adjacency A_hat in LDS +
//   activation constants cpos/cneg (b1==0 fast path) + exact fallback flag.
// Phase 2: role r of element e computes s[rows], z[rows]; z exchanged via
//   padded LDS; layer 2 on own rows; output staged in LDS and stored with
//   perfectly coalesced lane-stride-4B writes.
// NOTE: harness narrows int64 inputs to int32 -> ei is const int*,
//       src=[0,E), dst=[E,2E).
// ---------------------------------------------------------------------------
__global__ __launch_bounds__(TPB, 2) void gcn_fused_kernel(
    const float* __restrict__ x, const int* __restrict__ ei, int E,
    const float* __restrict__ W1, const float* __restrict__ b1,
    const float* __restrict__ W2, const float* __restrict__ b2,
    float* __restrict__ out, int B) {
  __shared__ __align__(16) float A[NN * NN];
  __shared__ float dinv[NN];
  __shared__ float cpos_s, cneg_s;
  __shared__ int flag_s;
  __shared__ float xchg[EPB * LSTR];  // 256*29 floats = 29.7 KB

  const int t = threadIdx.x;

  // ---- Phase 1: build A_hat in LDS ----
  if (t < NN) dinv[t] = 1.0f;  // self-loop contributes 1 to every degree
  for (int i = t; i < NN * NN; i += TPB) A[i] = 0.0f;
  if (t == 0) { cpos_s = 0.0f; cneg_s = 0.0f; flag_s = 0; }
  __syncthreads();

  for (int e = t; e < E; e += TPB) atomicAdd(&dinv[ei[E + e]], 1.0f);
  __syncthreads();
  if (t < NN) dinv[t] = 1.0f / sqrtf(dinv[t]);  // deg >= 1 always
  __syncthreads();

  for (int e = t; e < E; e += TPB) {
    int s = ei[e];
    int d = ei[E + e];
    atomicAdd(&A[d * NN + s], dinv[s] * dinv[d]);
  }
  if (t < NN) atomicAdd(&A[t * NN + t], dinv[t] * dinv[t]);  // self loops

  // activation constants: f(v) = sum_o relu(W1[o]*v + b1[o]) * W2[o]
  // if b1 == 0: f(v) = v * (v>0 ? cpos : cneg)
  if (t < NH) {
    float w1 = W1[t], w2 = W2[t];
    if (w1 > 0.0f)      atomicAdd(&cpos_s, w1 * w2);
    else if (w1 < 0.0f) atomicAdd(&cneg_s, w1 * w2);
    if (b1[t] != 0.0f) atomicOr(&flag_s, 1);
  }
  __syncthreads();

  // ---- Phase 2 ----
  const int elem = t & (EPB - 1);   // wave lanes have consecutive elems
  const int role = t >> 8;          // 0: rows 0-13, 1: rows 14-27
  const int row0 = role * 14;
  const int b = blockIdx.x * EPB + elem;
  const bool valid = (b < B);

  // load this element's 28 inputs (7 x float4; both roles load — cached)
  float xv[NN];
  if (valid) {
    const float4* xp = (const float4*)(x + (size_t)b * NN);
#pragma unroll
    for (int k = 0; k < 7; ++k) {
      float4 v = xp[k];
      xv[4 * k + 0] = v.x; xv[4 * k + 1] = v.y;
      xv[4 * k + 2] = v.z; xv[4 * k + 3] = v.w;
    }
  } else {
#pragma unroll
    for (int m = 0; m < NN; ++m) xv[m] = 0.0f;
  }

  const float4* A4 = (const float4*)A;  // rows are 7 float4 (112 B, aligned)

  // layer 1: my 14 rows of s = A @ xv   (A reads are wave-broadcast -> free)
  float s14[14];
#pragma unroll
  for (int i = 0; i < 14; ++i) {
    const int n = row0 + i;
    float a0 = 0.0f, a1 = 0.0f;
#pragma unroll
    for (int k = 0; k < 7; ++k) {
      float4 a = A4[n * 7 + k];
      a0 = fmaf(a.x, xv[4 * k + 0], a0);
      a1 = fmaf(a.y, xv[4 * k + 1], a1);
      a0 = fmaf(a.z, xv[4 * k + 2], a0);
      a1 = fmaf(a.w, xv[4 * k + 3], a1);
    }
    s14[i] = a0 + a1;
  }

  // activation
  const float cpos = cpos_s;
  const float cneg = cneg_s;
  float z14[14];
  if (flag_s == 0) {
#pragma unroll
    for (int i = 0; i < 14; ++i)
      z14[i] = s14[i] * (s14[i] > 0.0f ? cpos : cneg);
  } else {  // exact fallback (b1 != 0)
#pragma unroll
    for (int i = 0; i < 14; ++i) z14[i] = 0.0f;
    for (int o = 0; o < NH; ++o) {
      float w1 = W1[o], bb = b1[o], w2 = W2[o];
#pragma unroll
      for (int i = 0; i < 14; ++i)
        z14[i] = fmaf(fmaxf(fmaf(s14[i], w1, bb), 0.0f), w2, z14[i]);
    }
  }

  // exchange z between the two roles (padded stride -> conflict-free)
#pragma unroll
  for (int i = 0; i < 14; ++i) xchg[elem * LSTR + row0 + i] = z14[i];
  __syncthreads();

  float zv[NN];
#pragma unroll
  for (int j = 0; j < NN; ++j) zv[j] = xchg[elem * LSTR + j];

  // layer 2: my 14 rows of out = A @ zv + b2
  const float bias2 = b2[0];
  float o14[14];
#pragma unroll
  for (int i = 0; i < 14; ++i) {
    const int n = row0 + i;
    float a0 = bias2, a1 = 0.0f;
#pragma unroll
    for (int k = 0; k < 7; ++k) {
      float4 a = A4[n * 7 + k];
      a0 = fmaf(a.x, zv[4 * k + 0], a0);
      a1 = fmaf(a.y, zv[4 * k + 1], a1);
      a0 = fmaf(a.z, zv[4 * k + 2], a0);
      a1 = fmaf(a.w, zv[4 * k + 3], a1);
    }
    o14[i] = a0 + a1;
  }

  // stage output in LDS (after all z reads are done), then coalesced store
  __syncthreads();
#pragma unroll
  for (int i = 0; i < 14; ++i) xchg[elem * LSTR + row0 + i] = o14[i];
  __syncthreads();

  const size_t blk_base = (size_t)blockIdx.x * (EPB * NN);
  const size_t total = (size_t)B * NN;
#pragma unroll
  for (int k = 0; k < 14; ++k) {
    unsigned g = (unsigned)t + (unsigned)k * TPB;  // 0..7167
    unsigned e = g / NN;                            // magic-mul division
    unsigned j = g - e * NN;
    size_t gi = blk_base + g;
    if (gi < total) out[gi] = xchg[e * LSTR + j];   // lane-stride 4B: coalesced
  }
}

extern "C" void kernel_launch(void* const* d_in, const int* in_sizes, int n_in,
                              void* d_out, int out_size, void* d_ws, size_t ws_size,
                              hipStream_t stream) {
  const float* x  = (const float*)d_in[0];
  const int*   ei = (const int*)d_in[1];
  const float* W1 = (const float*)d_in[2];
  const float* b1 = (const float*)d_in[3];
  const float* W2 = (const float*)d_in[4];
  const float* b2 = (const float*)d_in[5];
  float* out = (float*)d_out;

  const int E = in_sizes[1] / 2;   // edge_index is (2, E)
  const int B = in_sizes[0] / NN;  // x is (B, 28)

  const int blocks = (B + EPB - 1) / EPB;  // 256 blocks, 512 threads: 8 waves/CU
  gcn_fused_kernel<<<blocks, TPB, 0, stream>>>(x, ei, E, W1, b1, W2, b2, out, B);
}

// Round 5
// 75.148 us; speedup vs baseline: 1.1707x; 1.0282x over previous
//
#include <hip/hip_runtime.h>
#include <math.h>

#define NN   28   // nodes
#define NH   64   // hidden dim
#define WAVES 8   // waves per block
#define TPB  (WAVES * 64)
#define EPW  16   // batch elements per wave (MFMA M=16)
#define EPB  (WAVES * EPW)   // 128 elements per block
#define ZSTR 29   // padded LDS stride for transpose buffer

typedef __attribute__((ext_vector_type(8))) short bf16x8;  // 8 bf16 = 4 VGPR
typedef __attribute__((ext_vector_type(4))) float f32x4;   // MFMA C/D frag

// fp32 -> bf16 round-to-nearest-even (finite inputs)
static __device__ __forceinline__ short f2bf(float f) {
  unsigned u = __float_as_uint(f);
  u = (u + 0x7FFFu + ((u >> 16) & 1u)) >> 16;
  return (short)u;
}
static __device__ __forceinline__ float bf2f(short h) {
  return __uint_as_float(((unsigned)(unsigned short)h) << 16);
}

// ---------------------------------------------------------------------------
// Fused MFMA kernel. Per block: build A_hat (28x28) in LDS (redundant, cheap),
// then each wave computes 16 batch elements via split-bf16 MFMA GEMM:
//   S = X A^T ; Z = f(S) ; O = Z A^T + b2
// Split-bf16: M ~= Mhi+Mlo, 3 products (hi*hi + lo*hi + hi*lo) ~ fp32 accuracy.
// Fragment layouts (learn_hip m89/m120 verified):
//   A-op: A[m=lane&15][k=(lane>>4)*8+j]  (j=0..7)
//   B-op: B[k=(lane>>4)*8+j][n=lane&15]
//   C/D : D[m=(lane>>4)*4+r][n=lane&15]  (r=0..3)
// NOTE: harness narrows int64 inputs to int32 -> ei is const int*,
//       src=[0,E), dst=[E,2E).
// ---------------------------------------------------------------------------
__global__ __launch_bounds__(TPB) void gcn_mfma_kernel(
    const float* __restrict__ x, const int* __restrict__ ei, int E,
    const float* __restrict__ W1, const float* __restrict__ b1,
    const float* __restrict__ W2, const float* __restrict__ b2,
    float* __restrict__ out, int B) {
  __shared__ __align__(16) float A[NN * NN];
  __shared__ float dinv[NN];
  __shared__ float cpos_s, cneg_s;
  __shared__ int flag_s;
  __shared__ float zbuf[WAVES][EPW * ZSTR];  // wave-private transpose buffers

  const int t = threadIdx.x;
  const int wave = t >> 6, lane = t & 63;
  const int q = lane >> 4, l15 = lane & 15;

  // ---- issue x loads early (latency hidden behind phase 1) ----
  const int gelem0 = (blockIdx.x * WAVES + wave) * EPW;  // this wave's 16 elems
  const int me = gelem0 + l15;                           // my A-frag elem (M)
  const bool mv = (me < B);
  const float* xr = x + (size_t)(mv ? me : 0) * NN + q * 8;  // 16B-aligned
  float4 xv0 = *(const float4*)xr;                           // k = q*8..q*8+3
  float4 xv1;                                                // k = q*8+4..+7
  if (q < 3) xv1 = *(const float4*)(xr + 4);
  else       xv1 = make_float4(0.f, 0.f, 0.f, 0.f);          // k=28..31 pad
  if (!mv) { xv0 = make_float4(0.f,0.f,0.f,0.f); xv1 = make_float4(0.f,0.f,0.f,0.f); }

  // ---- Phase 1: build A_hat in LDS (unchanged, verified) ----
  if (t < NN) dinv[t] = 1.0f;  // self-loop contributes 1 to every degree
  for (int i = t; i < NN * NN; i += TPB) A[i] = 0.0f;
  if (t == 0) { cpos_s = 0.0f; cneg_s = 0.0f; flag_s = 0; }
  __syncthreads();

  for (int e = t; e < E; e += TPB) atomicAdd(&dinv[ei[E + e]], 1.0f);
  __syncthreads();
  if (t < NN) dinv[t] = 1.0f / sqrtf(dinv[t]);  // deg >= 1 always
  __syncthreads();

  for (int e = t; e < E; e += TPB) {
    int s = ei[e];
    int d = ei[E + e];
    atomicAdd(&A[d * NN + s], dinv[s] * dinv[d]);
  }
  if (t < NN) atomicAdd(&A[t * NN + t], dinv[t] * dinv[t]);  // self loops

  // activation constants: f(v) = sum_o relu(W1[o]*v + b1[o]) * W2[o]
  // if b1 == 0: f(v) = v * (v>0 ? cpos : cneg)
  if (t < NH) {
    float w1 = W1[t], w2 = W2[t];
    if (w1 > 0.0f)      atomicAdd(&cpos_s, w1 * w2);
    else if (w1 < 0.0f) atomicAdd(&cneg_s, w1 * w2);
    if (b1[t] != 0.0f) atomicOr(&flag_s, 1);
  }
  __syncthreads();

  // ---- Build B-operand frags for A^T (once; reused by both layers) ----
  // B[k][n] = A_hat[n][k]; tile tt covers n = tt*16 + l15 (n>=28 -> 0)
  bf16x8 bhi0, bhi1, blo0, blo1;
  {
    const int n0 = l15, n1 = 16 + l15;
#pragma unroll
    for (int j = 0; j < 8; ++j) {
      const int k = q * 8 + j;
      float a0 = (k < NN) ? A[n0 * NN + k] : 0.0f;
      float a1 = (n1 < NN && k < NN) ? A[n1 * NN + k] : 0.0f;
      short h0 = f2bf(a0), h1 = f2bf(a1);
      bhi0[j] = h0; blo0[j] = f2bf(a0 - bf2f(h0));
      bhi1[j] = h1; blo1[j] = f2bf(a1 - bf2f(h1));
    }
  }

  // ---- X A-operand frag, split hi/lo ----
  bf16x8 xhi, xlo;
  {
    float xf[8] = {xv0.x, xv0.y, xv0.z, xv0.w, xv1.x, xv1.y, xv1.z, xv1.w};
#pragma unroll
    for (int j = 0; j < 8; ++j) {
      short h = f2bf(xf[j]);
      xhi[j] = h; xlo[j] = f2bf(xf[j] - bf2f(h));
    }
  }

  // ---- Layer 1: S = X A^T (3-product split-bf16) ----
  f32x4 acc0 = {0.f, 0.f, 0.f, 0.f}, acc1 = {0.f, 0.f, 0.f, 0.f};
  acc0 = __builtin_amdgcn_mfma_f32_16x16x32_bf16(xhi, bhi0, acc0, 0, 0, 0);
  acc0 = __builtin_amdgcn_mfma_f32_16x16x32_bf16(xlo, bhi0, acc0, 0, 0, 0);
  acc0 = __builtin_amdgcn_mfma_f32_16x16x32_bf16(xhi, blo0, acc0, 0, 0, 0);
  acc1 = __builtin_amdgcn_mfma_f32_16x16x32_bf16(xhi, bhi1, acc1, 0, 0, 0);
  acc1 = __builtin_amdgcn_mfma_f32_16x16x32_bf16(xlo, bhi1, acc1, 0, 0, 0);
  acc1 = __builtin_amdgcn_mfma_f32_16x16x32_bf16(xhi, blo1, acc1, 0, 0, 0);

  // ---- Activation ----
  const float cpos = cpos_s, cneg = cneg_s;
  float z0[4], z1[4];
  if (flag_s == 0) {
#pragma unroll
    for (int r = 0; r < 4; ++r) {
      z0[r] = acc0[r] * (acc0[r] > 0.0f ? cpos : cneg);
      z1[r] = acc1[r] * (acc1[r] > 0.0f ? cpos : cneg);
    }
  } else {  // exact fallback (b1 != 0)
#pragma unroll
    for (int r = 0; r < 4; ++r) { z0[r] = 0.0f; z1[r] = 0.0f; }
    for (int o = 0; o < NH; ++o) {
      float w1 = W1[o], bb = b1[o], w2 = W2[o];
#pragma unroll
      for (int r = 0; r < 4; ++r) {
        z0[r] = fmaf(fmaxf(fmaf(acc0[r], w1, bb), 0.0f), w2, z0[r]);
        z1[r] = fmaf(fmaxf(fmaf(acc1[r], w1, bb), 0.0f), w2, z1[r]);
      }
    }
  }

  // ---- C-layout -> A-operand relayout via wave-private LDS ----
  float* zb = zbuf[wave];
#pragma unroll
  for (int r = 0; r < 4; ++r) {
    const int m = q * 4 + r;               // local elem index
    zb[m * ZSTR + l15] = z0[r];            // n = 0..15
    if (l15 < NN - 16) zb[m * ZSTR + 16 + l15] = z1[r];  // n = 16..27
  }
  __builtin_amdgcn_wave_barrier();         // wave-synchronous LDS exchange

  bf16x8 zhi, zlo;
#pragma unroll
  for (int j = 0; j < 8; ++j) {
    const int k = q * 8 + j;
    float v = (k < NN) ? zb[l15 * ZSTR + k] : 0.0f;
    short h = f2bf(v);
    zhi[j] = h; zlo[j] = f2bf(v - bf2f(h));
  }
  __builtin_amdgcn_wave_barrier();

  // ---- Layer 2: O = Z A^T + b2 ----
  f32x4 occ0 = {0.f, 0.f, 0.f, 0.f}, occ1 = {0.f, 0.f, 0.f, 0.f};
  occ0 = __builtin_amdgcn_mfma_f32_16x16x32_bf16(zhi, bhi0, occ0, 0, 0, 0);
  occ0 = __builtin_amdgcn_mfma_f32_16x16x32_bf16(zlo, bhi0, occ0, 0, 0, 0);
  occ0 = __builtin_amdgcn_mfma_f32_16x16x32_bf16(zhi, blo0, occ0, 0, 0, 0);
  occ1 = __builtin_amdgcn_mfma_f32_16x16x32_bf16(zhi, bhi1, occ1, 0, 0, 0);
  occ1 = __builtin_amdgcn_mfma_f32_16x16x32_bf16(zlo, bhi1, occ1, 0, 0, 0);
  occ1 = __builtin_amdgcn_mfma_f32_16x16x32_bf16(zhi, blo1, occ1, 0, 0, 0);

  // ---- stage O in LDS, store coalesced ----
  const float bias2 = b2[0];
#pragma unroll
  for (int r = 0; r < 4; ++r) {
    const int m = q * 4 + r;
    zb[m * ZSTR + l15] = occ0[r] + bias2;
    if (l15 < NN - 16) zb[m * ZSTR + 16 + l15] = occ1[r] + bias2;
  }
  __builtin_amdgcn_wave_barrier();

  const size_t obase = (size_t)gelem0 * NN;
  const size_t total = (size_t)B * NN;
#pragma unroll
  for (int k7 = 0; k7 < 7; ++k7) {         // 16*28 = 448 = 64 lanes * 7
    const int flat = lane + 64 * k7;
    const unsigned e = (unsigned)flat / NN;  // const div -> magic mul
    const unsigned n = (unsigned)flat - e * NN;
    if (obase + flat < total)
      out[obase + flat] = zb[e * ZSTR + n];  // lane-stride 4B: coalesced
  }
}

extern "C" void kernel_launch(void* const* d_in, const int* in_sizes, int n_in,
                              void* d_out, int out_size, void* d_ws, size_t ws_size,
                              hipStream_t stream) {
  const float* x  = (const float*)d_in[0];
  const int*   ei = (const int*)d_in[1];
  const float* W1 = (const float*)d_in[2];
  const float* b1 = (const float*)d_in[3];
  const float* W2 = (const float*)d_in[4];
  const float* b2 = (const float*)d_in[5];
  float* out = (float*)d_out;

  const int E = in_sizes[1] / 2;   // edge_index is (2, E)
  const int B = in_sizes[0] / NN;  // x is (B, 28)

  const int blocks = (B + EPB - 1) / EPB;  // 512 blocks x 512 threads
  gcn_mfma_kernel<<<blocks, TPB, 0, stream>>>(x, ei, E, W1, b1, W2, b2, out, B);
}